// Round 7
// baseline (395.023 us; speedup 1.0000x reference)
//
#include <hip/hip_runtime.h>

#define ELLW 64          // max in-degree capacity (Poisson(16): P(deg>=64) ~ 2e-18)
#define BSHIFT 9         // nodes per bucket = 512
#define BNODES 512
#define NBUCK  256       // compile-time cap (supports N <= 131072)
#define BCAP   12288     // edge capacity per bucket (mean 8192, +45 sigma)

typedef __attribute__((ext_vector_type(8))) short short8v;  // 8 bf16 (4 VGPR)
typedef __attribute__((ext_vector_type(4))) float f32x4;    // MFMA accumulator

__device__ inline unsigned short bf16_rne(float x) {
    unsigned u = __float_as_uint(x);
    u += 0x7FFFu + ((u >> 16) & 1u);
    return (unsigned short)(u >> 16);
}
__device__ inline float bf16_to_f32(unsigned short h) {
    return __uint_as_float(((unsigned)h) << 16);
}

// ---------------------------------------------------------------------------
// Pass 1: partition edges into dst-range buckets (LDS-staged, rank-remember).
// ---------------------------------------------------------------------------
__global__ __launch_bounds__(256) void partition_kernel(
    const int* __restrict__ src, const int* __restrict__ dst, int E,
    uint2* __restrict__ part, int* __restrict__ gtail)
{
    __shared__ int scnt[NBUCK];
    __shared__ int sbase[NBUCK];
    const int t = threadIdx.x;
    #pragma unroll
    for (int i = t; i < NBUCK; i += 256) scnt[i] = 0;
    __syncthreads();

    const int e0 = blockIdx.x * 2048;
    int sarr[8], darr[8], rk[8];
    #pragma unroll
    for (int i = 0; i < 8; ++i) {
        int e = e0 + t + i * 256;
        if (e < E) {
            sarr[i] = src[e];
            darr[i] = dst[e];
            rk[i] = atomicAdd(&scnt[darr[i] >> BSHIFT], 1);
        }
    }
    __syncthreads();
    for (int i = t; i < NBUCK; i += 256)
        sbase[i] = scnt[i] ? atomicAdd(&gtail[i], scnt[i]) : 0;
    __syncthreads();
    #pragma unroll
    for (int i = 0; i < 8; ++i) {
        int e = e0 + t + i * 256;
        if (e < E) {
            int b = darr[i] >> BSHIFT;
            int p = sbase[b] + rk[i];
            if (p < BCAP)
                part[(size_t)b * BCAP + p] = make_uint2((unsigned)sarr[i], (unsigned)darr[i]);
        }
    }
}

// ---------------------------------------------------------------------------
// Pass 2: build each bucket's ELL slab entirely in LDS, stream out coalesced.
// Also writes degi + dinv. LDS 130 KB -> 1 block/CU.
// ---------------------------------------------------------------------------
__global__ __launch_bounds__(512) void ell_bucket_kernel(
    const uint2* __restrict__ part, const int* __restrict__ gcnt,
    int* __restrict__ degi, float* __restrict__ dinv,
    int* __restrict__ ell, int n)
{
    __shared__ int sdeg[BNODES];
    __shared__ int sell[BNODES * ELLW];

    const int b = blockIdx.x;
    const int t = threadIdx.x;
    sdeg[t] = 0;
    __syncthreads();

    int cnt = gcnt[b];
    if (cnt > BCAP) cnt = BCAP;
    const uint2* ep = part + (size_t)b * BCAP;
    for (int i = t; i < cnt; i += 512) {
        uint2 e = ep[i];
        int dl = (int)(e.y & (BNODES - 1));
        int pos = atomicAdd(&sdeg[dl], 1);
        if (pos < ELLW) sell[dl * ELLW + pos] = (int)e.x;
    }
    __syncthreads();

    const int node0 = b << BSHIFT;
    const int node = node0 + t;
    if (node < n) {
        int d = sdeg[t];
        degi[node] = d;
        dinv[node] = rsqrtf((float)d + 1.0f);
    }
    for (int f4 = t; f4 < BNODES * ELLW / 4; f4 += 512) {
        int nd = node0 + (f4 >> 4);
        if (nd < n) {
            int4 v = *(const int4*)&sell[f4 * 4];
            *(int4*)&ell[(size_t)node0 * ELLW + f4 * 4] = v;
        }
    }
}

// ---------------------------------------------------------------------------
// One-time W preprocess (all four weights, one launch): fp32 W[128][F] ->
// bf16 hi/lo planes, TRANSPOSED [F][128].
// ---------------------------------------------------------------------------
__global__ __launch_bounds__(256) void split_all_w_kernel(
    const float* __restrict__ W0, const float* __restrict__ W1,
    const float* __restrict__ Ws, const float* __restrict__ W2,
    unsigned short* __restrict__ W0hi, unsigned short* __restrict__ W0lo,
    unsigned short* __restrict__ W1hi, unsigned short* __restrict__ W1lo,
    unsigned short* __restrict__ Wshi, unsigned short* __restrict__ Wslo,
    unsigned short* __restrict__ W2hi, unsigned short* __restrict__ W2lo)
{
    int id = blockIdx.x * 256 + threadIdx.x;
    const float* W; unsigned short *Whi, *Wlo; int F, base;
    if (id < 16384)      { W = W0; Whi = W0hi; Wlo = W0lo; F = 128; base = 0; }
    else if (id < 32768) { W = W1; Whi = W1hi; Wlo = W1lo; F = 128; base = 16384; }
    else if (id < 49152) { W = Ws; Whi = Wshi; Wlo = Wslo; F = 128; base = 32768; }
    else if (id < 57344) { W = W2; Whi = W2hi; Wlo = W2lo; F = 64;  base = 49152; }
    else return;
    int l = id - base;
    int k = l / F, c = l % F;
    float x = W[l];
    unsigned short hi = bf16_rne(x);
    Whi[c * 128 + k] = hi;
    Wlo[c * 128 + k] = bf16_rne(x - bf16_to_f32(hi));
}

// ---------------------------------------------------------------------------
// LDS-free split-bf16 MFMA GEMM, 4x1 wave grid (each wave owns 32 unique
// rows, ALL F cols -> no duplicate A reads). Epilogue scales rows by dinv
// (pre-scaling for the gather) and writes bf16.
// ---------------------------------------------------------------------------
template<int F, bool AFP32>
__global__ __launch_bounds__(256) void mfma_gemm_scaled_kernel(
    const float* __restrict__ Af,
    const unsigned short* __restrict__ Ahi, const unsigned short* __restrict__ Alo,
    const unsigned short* __restrict__ BhiT, const unsigned short* __restrict__ BloT,
    const float* __restrict__ dinv, unsigned short* __restrict__ out, int nrows)
{
    constexpr int CG = F / 16;
    const int t    = threadIdx.x;
    const int lane = t & 63;
    const int wv   = t >> 6;
    const int l15  = lane & 15;
    const int lg   = lane >> 4;
    const int row0 = blockIdx.x * 128 + wv * 32;

    f32x4 acc[2][CG];
    #pragma unroll
    for (int mf = 0; mf < 2; ++mf)
        #pragma unroll
        for (int cg = 0; cg < CG; ++cg)
            acc[mf][cg] = (f32x4){0.f, 0.f, 0.f, 0.f};

    #pragma unroll
    for (int kk = 0; kk < 4; ++kk) {
        short8v ah[2], al[2];
        #pragma unroll
        for (int mf = 0; mf < 2; ++mf) {
            int row = row0 + mf * 16 + l15;
            int rl  = row < nrows ? row : 0;
            size_t ao = (size_t)rl * 128 + kk * 32 + lg * 8;
            if constexpr (AFP32) {
                const float* p = &Af[ao];
                float4 v0 = *(const float4*)p;
                float4 v1 = *(const float4*)(p + 4);
                float xs[8] = {v0.x, v0.y, v0.z, v0.w, v1.x, v1.y, v1.z, v1.w};
                short8v h, l;
                #pragma unroll
                for (int j = 0; j < 8; ++j) {
                    unsigned short hb = bf16_rne(xs[j]);
                    h[j] = (short)hb;
                    l[j] = (short)bf16_rne(xs[j] - bf16_to_f32(hb));
                }
                ah[mf] = h; al[mf] = l;
            } else {
                ah[mf] = *(const short8v*)&Ahi[ao];
                al[mf] = *(const short8v*)&Alo[ao];
            }
        }
        #pragma unroll
        for (int cg = 0; cg < CG; ++cg) {
            int col = cg * 16 + l15;
            size_t bo = (size_t)col * 128 + kk * 32 + lg * 8;
            short8v bh = *(const short8v*)&BhiT[bo];
            short8v bl = *(const short8v*)&BloT[bo];
            #pragma unroll
            for (int mf = 0; mf < 2; ++mf) {
                acc[mf][cg] = __builtin_amdgcn_mfma_f32_16x16x32_bf16(ah[mf], bh, acc[mf][cg], 0, 0, 0);
                acc[mf][cg] = __builtin_amdgcn_mfma_f32_16x16x32_bf16(ah[mf], bl, acc[mf][cg], 0, 0, 0);
                acc[mf][cg] = __builtin_amdgcn_mfma_f32_16x16x32_bf16(al[mf], bh, acc[mf][cg], 0, 0, 0);
            }
        }
    }

    // epilogue: C/D layout col=lane&15, row=(lane>>4)*4+reg; scale by dinv
    #pragma unroll
    for (int mf = 0; mf < 2; ++mf) {
        int rbase = row0 + mf * 16 + lg * 4;
        float dv[4];
        #pragma unroll
        for (int r = 0; r < 4; ++r)
            dv[r] = (rbase + r < nrows) ? dinv[rbase + r] : 0.f;
        #pragma unroll
        for (int cg = 0; cg < CG; ++cg) {
            int col = cg * 16 + l15;
            #pragma unroll
            for (int r = 0; r < 4; ++r) {
                int row = rbase + r;
                if (row < nrows)
                    out[(size_t)row * F + col] = bf16_rne(acc[mf][cg][r] * dv[r]);
            }
        }
    }
}

// ---------------------------------------------------------------------------
// Fused dual GEMM for layer 1 (shared A = h1 hi/lo planes), 512 thr = 8 waves
// in a 4x2 grid: wm=wv>>1 picks 32-row band, wn=wv&1 picks 64-col half.
//   outS = A@Ws + bs          (skip branch, bf16)
//   outM = dinv .* (A@W1)     (pre-scaled gather operand, bf16)
// ---------------------------------------------------------------------------
__global__ __launch_bounds__(512) void mfma_gemm_dual_kernel(
    const unsigned short* __restrict__ Ahi, const unsigned short* __restrict__ Alo,
    const unsigned short* __restrict__ WsHiT, const unsigned short* __restrict__ WsLoT,
    const unsigned short* __restrict__ W1HiT, const unsigned short* __restrict__ W1LoT,
    const float* __restrict__ bias_s, const float* __restrict__ dinv,
    unsigned short* __restrict__ outS, unsigned short* __restrict__ outM, int nrows)
{
    const int t    = threadIdx.x;
    const int lane = t & 63;
    const int wv   = t >> 6;
    const int wm   = wv >> 1;          // 0..3: 32-row band
    const int wn   = wv & 1;           // 0..1: 64-col half
    const int l15  = lane & 15;
    const int lg   = lane >> 4;
    const int row0 = blockIdx.x * 128 + wm * 32;

    f32x4 accS[2][4], accM[2][4];
    #pragma unroll
    for (int mf = 0; mf < 2; ++mf)
        #pragma unroll
        for (int cg = 0; cg < 4; ++cg) {
            accS[mf][cg] = (f32x4){0.f, 0.f, 0.f, 0.f};
            accM[mf][cg] = (f32x4){0.f, 0.f, 0.f, 0.f};
        }

    #pragma unroll
    for (int kk = 0; kk < 4; ++kk) {
        short8v ah[2], al[2];
        #pragma unroll
        for (int mf = 0; mf < 2; ++mf) {
            int row = row0 + mf * 16 + l15;
            int rl  = row < nrows ? row : 0;
            size_t ao = (size_t)rl * 128 + kk * 32 + lg * 8;
            ah[mf] = *(const short8v*)&Ahi[ao];
            al[mf] = *(const short8v*)&Alo[ao];
        }
        #pragma unroll
        for (int cg = 0; cg < 4; ++cg) {
            int col = wn * 64 + cg * 16 + l15;
            size_t bo = (size_t)col * 128 + kk * 32 + lg * 8;
            short8v sh = *(const short8v*)&WsHiT[bo];
            short8v sl = *(const short8v*)&WsLoT[bo];
            #pragma unroll
            for (int mf = 0; mf < 2; ++mf) {
                accS[mf][cg] = __builtin_amdgcn_mfma_f32_16x16x32_bf16(ah[mf], sh, accS[mf][cg], 0, 0, 0);
                accS[mf][cg] = __builtin_amdgcn_mfma_f32_16x16x32_bf16(ah[mf], sl, accS[mf][cg], 0, 0, 0);
                accS[mf][cg] = __builtin_amdgcn_mfma_f32_16x16x32_bf16(al[mf], sh, accS[mf][cg], 0, 0, 0);
            }
            short8v oh = *(const short8v*)&W1HiT[bo];
            short8v ol = *(const short8v*)&W1LoT[bo];
            #pragma unroll
            for (int mf = 0; mf < 2; ++mf) {
                accM[mf][cg] = __builtin_amdgcn_mfma_f32_16x16x32_bf16(ah[mf], oh, accM[mf][cg], 0, 0, 0);
                accM[mf][cg] = __builtin_amdgcn_mfma_f32_16x16x32_bf16(ah[mf], ol, accM[mf][cg], 0, 0, 0);
                accM[mf][cg] = __builtin_amdgcn_mfma_f32_16x16x32_bf16(al[mf], oh, accM[mf][cg], 0, 0, 0);
            }
        }
    }

    #pragma unroll
    for (int mf = 0; mf < 2; ++mf) {
        int rbase = row0 + mf * 16 + lg * 4;
        float dv[4];
        #pragma unroll
        for (int r = 0; r < 4; ++r)
            dv[r] = (rbase + r < nrows) ? dinv[rbase + r] : 0.f;
        #pragma unroll
        for (int cg = 0; cg < 4; ++cg) {
            int col = wn * 64 + cg * 16 + l15;
            float bv = bias_s[col];
            #pragma unroll
            for (int r = 0; r < 4; ++r) {
                int row = rbase + r;
                if (row < nrows) {
                    outS[(size_t)row * 128 + col] = bf16_rne(accS[mf][cg][r] + bv);
                    outM[(size_t)row * 128 + col] = bf16_rne(accM[mf][cg][r] * dv[r]);
                }
            }
        }
    }
}

// ---------------------------------------------------------------------------
// Aggregation over PRE-SCALED bf16 rows (hw'[j] = dinv_j * hw[j]):
//   r = dinv_i * ( sum_j hw'_j + hw'_i ) + bias
// No per-neighbor weight shuffle, no dinv gather. Dummy tail lanes gather a
// zeroed row at index `dummy` (adds 0).
// MODE 0: relu(r)        -> bf16 hi/lo planes   (h1)
// MODE 1: relu(r) + skip -> bf16 hi/lo planes   (h2)
// MODE 2: r              -> fp32 d_out          (F=64 output layer)
// ---------------------------------------------------------------------------
template<int F, int MODE>
__global__ __launch_bounds__(256) void agg_kernel(
    const unsigned short* __restrict__ hws, const int* __restrict__ ell,
    const int* __restrict__ degi, const float* __restrict__ dinv,
    const float* __restrict__ bias, const unsigned short* __restrict__ skip,
    unsigned* __restrict__ outHi, unsigned* __restrict__ outLo,
    float* __restrict__ outF, int n, int dummy)
{
    constexpr int VEC = F / 64;
    constexpr int UNR = 8;
    const int lane = threadIdx.x & 63;
    const int node = blockIdx.x * 4 + (threadIdx.x >> 6);
    if (node >= n) return;

    const int deg  = degi[node];
    const int kmax = deg < ELLW ? deg : ELLW;
    const float di = dinv[node];

    int jpre = dummy;
    if (lane < kmax) jpre = ell[node * ELLW + lane];

    float acc[4][VEC];
    #pragma unroll
    for (int u = 0; u < 4; ++u)
        #pragma unroll
        for (int v = 0; v < VEC; ++v) acc[u][v] = 0.f;

    // self-loop term: hw'_i (already dinv_i-scaled)
    if constexpr (VEC == 2) {
        unsigned p = *(const unsigned*)&hws[(size_t)node * F + lane * 2];
        acc[0][0] = bf16_to_f32((unsigned short)(p & 0xFFFF));
        acc[0][1] = bf16_to_f32((unsigned short)(p >> 16));
    } else {
        acc[0][0] = bf16_to_f32(hws[(size_t)node * F + lane]);
    }

    const int kceil = (kmax + UNR - 1) & ~(UNR - 1);
    for (int k = 0; k < kceil; k += UNR) {
        int jj[UNR];
        #pragma unroll
        for (int u = 0; u < UNR; ++u) jj[u] = __shfl(jpre, k + u);
        if constexpr (VEC == 2) {
            unsigned h[UNR];
            #pragma unroll
            for (int u = 0; u < UNR; ++u)
                h[u] = *(const unsigned*)&hws[(size_t)jj[u] * F + lane * 2];
            #pragma unroll
            for (int u = 0; u < UNR; ++u) {
                acc[u & 3][0] += bf16_to_f32((unsigned short)(h[u] & 0xFFFF));
                acc[u & 3][1] += bf16_to_f32((unsigned short)(h[u] >> 16));
            }
        } else {
            unsigned short h[UNR];
            #pragma unroll
            for (int u = 0; u < UNR; ++u)
                h[u] = hws[(size_t)jj[u] * F + lane];
            #pragma unroll
            for (int u = 0; u < UNR; ++u)
                acc[u & 3][0] += bf16_to_f32(h[u]);
        }
    }

    float r[VEC];
    #pragma unroll
    for (int v = 0; v < VEC; ++v) {
        float s = (acc[0][v] + acc[1][v]) + (acc[2][v] + acc[3][v]);
        r[v] = s * di + bias[lane * VEC + v];
    }

    if constexpr (MODE == 2) {
        outF[(size_t)node * F + lane] = r[0];
    } else {
        #pragma unroll
        for (int v = 0; v < VEC; ++v) {
            r[v] = fmaxf(r[v], 0.f);
            if (MODE == 1) {
                unsigned sp = *(const unsigned*)&skip[(size_t)node * F + lane * 2];
                float sv = (v == 0) ? bf16_to_f32((unsigned short)(sp & 0xFFFF))
                                    : bf16_to_f32((unsigned short)(sp >> 16));
                r[v] += sv;
            }
        }
        unsigned short h0 = bf16_rne(r[0]), h1 = bf16_rne(r[1]);
        unsigned short l0 = bf16_rne(r[0] - bf16_to_f32(h0));
        unsigned short l1 = bf16_rne(r[1] - bf16_to_f32(h1));
        size_t o = (size_t)node * (F / 2) + lane;
        outHi[o] = (unsigned)h0 | ((unsigned)h1 << 16);
        outLo[o] = (unsigned)l0 | ((unsigned)l1 << 16);
    }
}

// ---------------------------------------------------------------------------
extern "C" void kernel_launch(void* const* d_in, const int* in_sizes, int n_in,
                              void* d_out, int out_size, void* d_ws, size_t ws_size,
                              hipStream_t stream)
{
    const float* x  = (const float*)d_in[0];
    const int*   ei = (const int*)  d_in[1];
    const float* W0 = (const float*)d_in[2];
    const float* b0 = (const float*)d_in[3];
    const float* W1 = (const float*)d_in[4];
    const float* b1 = (const float*)d_in[5];
    const float* W2 = (const float*)d_in[6];
    const float* b2 = (const float*)d_in[7];
    const float* Ws = (const float*)d_in[8];
    const float* bs = (const float*)d_in[9];

    const int N = in_sizes[0] / 128;
    const int E = in_sizes[1] / 2;
    const int* src = ei;
    const int* dst = ei + E;

    char* ws = (char*)d_ws;
    auto al = [](size_t v) { return (v + 255) & ~size_t(255); };
    size_t off = 0;
    int*   degi  = (int*)  (ws + off); off = al(off + (size_t)N * 4);
    float* dinv  = (float*)(ws + off); off = al(off + (size_t)N * 4);
    int*   gtail = (int*)  (ws + off); off = al(off + NBUCK * 4);
    int*   ell   = (int*)  (ws + off); off = al(off + (size_t)N * ELLW * 4);
    uint2* part  = (uint2*)(ws + off); off = al(off + (size_t)NBUCK * BCAP * 8);
    unsigned short* pA   = (unsigned short*)(ws + off); off = al(off + ((size_t)N * 128 + 128) * 2);
    unsigned short* pBhi = (unsigned short*)(ws + off); off = al(off + (size_t)N * 128 * 2);
    unsigned short* pBlo = (unsigned short*)(ws + off); off = al(off + (size_t)N * 128 * 2);
    unsigned short* pC   = (unsigned short*)(ws + off); off = al(off + (size_t)N * 128 * 2);
    unsigned short* W0hi = (unsigned short*)(ws + off); off = al(off + 128 * 128 * 2);
    unsigned short* W0lo = (unsigned short*)(ws + off); off = al(off + 128 * 128 * 2);
    unsigned short* W1hi = (unsigned short*)(ws + off); off = al(off + 128 * 128 * 2);
    unsigned short* W1lo = (unsigned short*)(ws + off); off = al(off + 128 * 128 * 2);
    unsigned short* Wshi = (unsigned short*)(ws + off); off = al(off + 128 * 128 * 2);
    unsigned short* Wslo = (unsigned short*)(ws + off); off = al(off + 128 * 128 * 2);
    unsigned short* W2hi = (unsigned short*)(ws + off); off = al(off + 128 * 64 * 2);
    unsigned short* W2lo = (unsigned short*)(ws + off); off = al(off + 128 * 64 * 2);
    (void)ws_size; (void)n_in; (void)out_size;

    hipMemsetAsync(gtail, 0, NBUCK * 4, stream);
    hipMemsetAsync(pA + (size_t)N * 128, 0, 128 * 2, stream);  // zero dummy row
    partition_kernel<<<(E + 2047) / 2048, 256, 0, stream>>>(src, dst, E, part, gtail);
    ell_bucket_kernel<<<(N + BNODES - 1) / BNODES, 512, 0, stream>>>(
        part, gtail, degi, dinv, ell, N);
    split_all_w_kernel<<<224, 256, 0, stream>>>(
        W0, W1, Ws, W2, W0hi, W0lo, W1hi, W1lo, Wshi, Wslo, W2hi, W2lo);

    const int gg = (N + 127) / 128;
    const int ga = (N + 3) / 4;

    // layer 0: hw0' = dinv .* (x@W0);  h1 = relu(di*(sum hw0') + b0)
    mfma_gemm_scaled_kernel<128, true><<<gg, 256, 0, stream>>>(
        x, nullptr, nullptr, W0hi, W0lo, dinv, pA, N);
    agg_kernel<128, 0><<<ga, 256, 0, stream>>>(
        pA, ell, degi, dinv, b0, nullptr, (unsigned*)pBhi, (unsigned*)pBlo, nullptr, N, N);

    // layer 1 (fused): skip = h1@Ws + bs;  hw1' = dinv .* (h1@W1)
    mfma_gemm_dual_kernel<<<gg, 512, 0, stream>>>(
        pBhi, pBlo, Wshi, Wslo, W1hi, W1lo, bs, dinv, pC, pA, N);
    agg_kernel<128, 1><<<ga, 256, 0, stream>>>(
        pA, ell, degi, dinv, b1, pC, (unsigned*)pBhi, (unsigned*)pBlo, nullptr, N, N);

    // output layer: hw2' = dinv .* (h2@W2);  out = di*(sum hw2') + b2
    mfma_gemm_scaled_kernel<64, false><<<gg, 256, 0, stream>>>(
        nullptr, pBhi, pBlo, W2hi, W2lo, dinv, pA, N);
    agg_kernel<64, 2><<<ga, 256, 0, stream>>>(
        pA, ell, degi, dinv, b2, nullptr, nullptr, nullptr, (float*)d_out, N, 2 * N);
}

// Round 8
// 380.325 us; speedup vs baseline: 1.0386x; 1.0386x over previous
//
#include <hip/hip_runtime.h>

#define ELLW 64          // max in-degree capacity (Poisson(16): P(deg>=64) ~ 2e-18)
#define BSHIFT 9         // nodes per bucket = 512
#define BNODES 512
#define NBUCK  256       // compile-time cap (supports N <= 131072)
#define BCAP   12288     // edge capacity per bucket (mean 8192, +45 sigma)

typedef __attribute__((ext_vector_type(8))) short short8v;  // 8 bf16 (4 VGPR)
typedef __attribute__((ext_vector_type(4))) float f32x4;    // MFMA accumulator

__device__ inline unsigned short bf16_rne(float x) {
    unsigned u = __float_as_uint(x);
    u += 0x7FFFu + ((u >> 16) & 1u);
    return (unsigned short)(u >> 16);
}
__device__ inline float bf16_to_f32(unsigned short h) {
    return __uint_as_float(((unsigned)h) << 16);
}

// ---------------------------------------------------------------------------
// Pass 1: partition edges into dst-range buckets (LDS-staged, rank-remember).
// ---------------------------------------------------------------------------
__global__ __launch_bounds__(256) void partition_kernel(
    const int* __restrict__ src, const int* __restrict__ dst, int E,
    uint2* __restrict__ part, int* __restrict__ gtail)
{
    __shared__ int scnt[NBUCK];
    __shared__ int sbase[NBUCK];
    const int t = threadIdx.x;
    #pragma unroll
    for (int i = t; i < NBUCK; i += 256) scnt[i] = 0;
    __syncthreads();

    const int e0 = blockIdx.x * 2048;
    int sarr[8], darr[8], rk[8];
    #pragma unroll
    for (int i = 0; i < 8; ++i) {
        int e = e0 + t + i * 256;
        if (e < E) {
            sarr[i] = src[e];
            darr[i] = dst[e];
            rk[i] = atomicAdd(&scnt[darr[i] >> BSHIFT], 1);
        }
    }
    __syncthreads();
    for (int i = t; i < NBUCK; i += 256)
        sbase[i] = scnt[i] ? atomicAdd(&gtail[i], scnt[i]) : 0;
    __syncthreads();
    #pragma unroll
    for (int i = 0; i < 8; ++i) {
        int e = e0 + t + i * 256;
        if (e < E) {
            int b = darr[i] >> BSHIFT;
            int p = sbase[b] + rk[i];
            if (p < BCAP)
                part[(size_t)b * BCAP + p] = make_uint2((unsigned)sarr[i], (unsigned)darr[i]);
        }
    }
}

// ---------------------------------------------------------------------------
// Pass 2: build each bucket's ELL slab entirely in LDS, stream out coalesced.
// Also writes degi + dinv. LDS 130 KB -> 1 block/CU.
// ---------------------------------------------------------------------------
__global__ __launch_bounds__(512) void ell_bucket_kernel(
    const uint2* __restrict__ part, const int* __restrict__ gcnt,
    int* __restrict__ degi, float* __restrict__ dinv,
    int* __restrict__ ell, int n)
{
    __shared__ int sdeg[BNODES];
    __shared__ int sell[BNODES * ELLW];

    const int b = blockIdx.x;
    const int t = threadIdx.x;
    sdeg[t] = 0;
    __syncthreads();

    int cnt = gcnt[b];
    if (cnt > BCAP) cnt = BCAP;
    const uint2* ep = part + (size_t)b * BCAP;
    for (int i = t; i < cnt; i += 512) {
        uint2 e = ep[i];
        int dl = (int)(e.y & (BNODES - 1));
        int pos = atomicAdd(&sdeg[dl], 1);
        if (pos < ELLW) sell[dl * ELLW + pos] = (int)e.x;
    }
    __syncthreads();

    const int node0 = b << BSHIFT;
    const int node = node0 + t;
    if (node < n) {
        int d = sdeg[t];
        degi[node] = d;
        dinv[node] = rsqrtf((float)d + 1.0f);
    }
    for (int f4 = t; f4 < BNODES * ELLW / 4; f4 += 512) {
        int nd = node0 + (f4 >> 4);
        if (nd < n) {
            int4 v = *(const int4*)&sell[f4 * 4];
            *(int4*)&ell[(size_t)node0 * ELLW + f4 * 4] = v;
        }
    }
}

// ---------------------------------------------------------------------------
// One-time W preprocess (all four weights, one launch): fp32 W[128][F] ->
// bf16 hi/lo planes, TRANSPOSED [F][128].
// ---------------------------------------------------------------------------
__global__ __launch_bounds__(256) void split_all_w_kernel(
    const float* __restrict__ W0, const float* __restrict__ W1,
    const float* __restrict__ Ws, const float* __restrict__ W2,
    unsigned short* __restrict__ W0hi, unsigned short* __restrict__ W0lo,
    unsigned short* __restrict__ W1hi, unsigned short* __restrict__ W1lo,
    unsigned short* __restrict__ Wshi, unsigned short* __restrict__ Wslo,
    unsigned short* __restrict__ W2hi, unsigned short* __restrict__ W2lo)
{
    int id = blockIdx.x * 256 + threadIdx.x;
    const float* W; unsigned short *Whi, *Wlo; int F, base;
    if (id < 16384)      { W = W0; Whi = W0hi; Wlo = W0lo; F = 128; base = 0; }
    else if (id < 32768) { W = W1; Whi = W1hi; Wlo = W1lo; F = 128; base = 16384; }
    else if (id < 49152) { W = Ws; Whi = Wshi; Wlo = Wslo; F = 128; base = 32768; }
    else if (id < 57344) { W = W2; Whi = W2hi; Wlo = W2lo; F = 64;  base = 49152; }
    else return;
    int l = id - base;
    int k = l / F, c = l % F;
    float x = W[l];
    unsigned short hi = bf16_rne(x);
    Whi[c * 128 + k] = hi;
    Wlo[c * 128 + k] = bf16_rne(x - bf16_to_f32(hi));
}

// ---------------------------------------------------------------------------
// LDS-free split-bf16 MFMA GEMM, 4x1 wave grid (each wave owns 32 unique
// rows, ALL F cols). A-fragment loads HOISTED (16 independent 16B loads in
// flight) for the bf16 path. Epilogue scales rows by dinv, writes bf16.
// ---------------------------------------------------------------------------
template<int F, bool AFP32>
__global__ __launch_bounds__(256) void mfma_gemm_scaled_kernel(
    const float* __restrict__ Af,
    const unsigned short* __restrict__ Ahi, const unsigned short* __restrict__ Alo,
    const unsigned short* __restrict__ BhiT, const unsigned short* __restrict__ BloT,
    const float* __restrict__ dinv, unsigned short* __restrict__ out, int nrows)
{
    constexpr int CG = F / 16;
    const int t    = threadIdx.x;
    const int lane = t & 63;
    const int wv   = t >> 6;
    const int l15  = lane & 15;
    const int lg   = lane >> 4;
    const int row0 = blockIdx.x * 128 + wv * 32;

    // ---- hoisted A fragments: [mf][kk] ----
    short8v ah[2][4], al[2][4];
    #pragma unroll
    for (int mf = 0; mf < 2; ++mf) {
        int row = row0 + mf * 16 + l15;
        int rl  = row < nrows ? row : 0;
        #pragma unroll
        for (int kk = 0; kk < 4; ++kk) {
            size_t ao = (size_t)rl * 128 + kk * 32 + lg * 8;
            if constexpr (AFP32) {
                const float* p = &Af[ao];
                float4 v0 = *(const float4*)p;
                float4 v1 = *(const float4*)(p + 4);
                float xs[8] = {v0.x, v0.y, v0.z, v0.w, v1.x, v1.y, v1.z, v1.w};
                short8v h, l;
                #pragma unroll
                for (int j = 0; j < 8; ++j) {
                    unsigned short hb = bf16_rne(xs[j]);
                    h[j] = (short)hb;
                    l[j] = (short)bf16_rne(xs[j] - bf16_to_f32(hb));
                }
                ah[mf][kk] = h; al[mf][kk] = l;
            } else {
                ah[mf][kk] = *(const short8v*)&Ahi[ao];
                al[mf][kk] = *(const short8v*)&Alo[ao];
            }
        }
    }

    f32x4 acc[2][CG];
    #pragma unroll
    for (int mf = 0; mf < 2; ++mf)
        #pragma unroll
        for (int cg = 0; cg < CG; ++cg)
            acc[mf][cg] = (f32x4){0.f, 0.f, 0.f, 0.f};

    #pragma unroll
    for (int kk = 0; kk < 4; ++kk) {
        #pragma unroll
        for (int cg = 0; cg < CG; ++cg) {
            int col = cg * 16 + l15;
            size_t bo = (size_t)col * 128 + kk * 32 + lg * 8;
            short8v bh = *(const short8v*)&BhiT[bo];
            short8v bl = *(const short8v*)&BloT[bo];
            #pragma unroll
            for (int mf = 0; mf < 2; ++mf) {
                acc[mf][cg] = __builtin_amdgcn_mfma_f32_16x16x32_bf16(ah[mf][kk], bh, acc[mf][cg], 0, 0, 0);
                acc[mf][cg] = __builtin_amdgcn_mfma_f32_16x16x32_bf16(ah[mf][kk], bl, acc[mf][cg], 0, 0, 0);
                acc[mf][cg] = __builtin_amdgcn_mfma_f32_16x16x32_bf16(al[mf][kk], bh, acc[mf][cg], 0, 0, 0);
            }
        }
    }

    // epilogue: C/D layout col=lane&15, row=(lane>>4)*4+reg; scale by dinv
    #pragma unroll
    for (int mf = 0; mf < 2; ++mf) {
        int rbase = row0 + mf * 16 + lg * 4;
        float dv[4];
        #pragma unroll
        for (int r = 0; r < 4; ++r)
            dv[r] = (rbase + r < nrows) ? dinv[rbase + r] : 0.f;
        #pragma unroll
        for (int cg = 0; cg < CG; ++cg) {
            int col = cg * 16 + l15;
            #pragma unroll
            for (int r = 0; r < 4; ++r) {
                int row = rbase + r;
                if (row < nrows)
                    out[(size_t)row * F + col] = bf16_rne(acc[mf][cg][r] * dv[r]);
            }
        }
    }
}

// ---------------------------------------------------------------------------
// Fused dual GEMM for layer 1 (shared A = h1 hi/lo planes).
// 256 thr = 4 waves, 2x2 grid over a 64-row x 128-col tile (wm: 32-row band,
// wn: 64-col half) -> 64 acc VGPR/wave, 4-wave blocks, ~3 blocks/CU.
// A-fragment loads hoisted.
//   outS = A@Ws + bs          (skip branch, bf16)
//   outM = dinv .* (A@W1)     (pre-scaled gather operand, bf16)
// ---------------------------------------------------------------------------
__global__ __launch_bounds__(256) void mfma_gemm_dual_kernel(
    const unsigned short* __restrict__ Ahi, const unsigned short* __restrict__ Alo,
    const unsigned short* __restrict__ WsHiT, const unsigned short* __restrict__ WsLoT,
    const unsigned short* __restrict__ W1HiT, const unsigned short* __restrict__ W1LoT,
    const float* __restrict__ bias_s, const float* __restrict__ dinv,
    unsigned short* __restrict__ outS, unsigned short* __restrict__ outM, int nrows)
{
    const int t    = threadIdx.x;
    const int lane = t & 63;
    const int wv   = t >> 6;
    const int wm   = wv >> 1;          // 0..1: 32-row band
    const int wn   = wv & 1;           // 0..1: 64-col half
    const int l15  = lane & 15;
    const int lg   = lane >> 4;
    const int row0 = blockIdx.x * 64 + wm * 32;

    // ---- hoisted A fragments: [mf][kk] ----
    short8v ah[2][4], al[2][4];
    #pragma unroll
    for (int mf = 0; mf < 2; ++mf) {
        int row = row0 + mf * 16 + l15;
        int rl  = row < nrows ? row : 0;
        #pragma unroll
        for (int kk = 0; kk < 4; ++kk) {
            size_t ao = (size_t)rl * 128 + kk * 32 + lg * 8;
            ah[mf][kk] = *(const short8v*)&Ahi[ao];
            al[mf][kk] = *(const short8v*)&Alo[ao];
        }
    }

    f32x4 accS[2][4], accM[2][4];
    #pragma unroll
    for (int mf = 0; mf < 2; ++mf)
        #pragma unroll
        for (int cg = 0; cg < 4; ++cg) {
            accS[mf][cg] = (f32x4){0.f, 0.f, 0.f, 0.f};
            accM[mf][cg] = (f32x4){0.f, 0.f, 0.f, 0.f};
        }

    #pragma unroll
    for (int kk = 0; kk < 4; ++kk) {
        #pragma unroll
        for (int cg = 0; cg < 4; ++cg) {
            int col = wn * 64 + cg * 16 + l15;
            size_t bo = (size_t)col * 128 + kk * 32 + lg * 8;
            short8v sh = *(const short8v*)&WsHiT[bo];
            short8v sl = *(const short8v*)&WsLoT[bo];
            short8v oh = *(const short8v*)&W1HiT[bo];
            short8v ol = *(const short8v*)&W1LoT[bo];
            #pragma unroll
            for (int mf = 0; mf < 2; ++mf) {
                accS[mf][cg] = __builtin_amdgcn_mfma_f32_16x16x32_bf16(ah[mf][kk], sh, accS[mf][cg], 0, 0, 0);
                accS[mf][cg] = __builtin_amdgcn_mfma_f32_16x16x32_bf16(ah[mf][kk], sl, accS[mf][cg], 0, 0, 0);
                accS[mf][cg] = __builtin_amdgcn_mfma_f32_16x16x32_bf16(al[mf][kk], sh, accS[mf][cg], 0, 0, 0);
                accM[mf][cg] = __builtin_amdgcn_mfma_f32_16x16x32_bf16(ah[mf][kk], oh, accM[mf][cg], 0, 0, 0);
                accM[mf][cg] = __builtin_amdgcn_mfma_f32_16x16x32_bf16(ah[mf][kk], ol, accM[mf][cg], 0, 0, 0);
                accM[mf][cg] = __builtin_amdgcn_mfma_f32_16x16x32_bf16(al[mf][kk], oh, accM[mf][cg], 0, 0, 0);
            }
        }
    }

    #pragma unroll
    for (int mf = 0; mf < 2; ++mf) {
        int rbase = row0 + mf * 16 + lg * 4;
        float dv[4];
        #pragma unroll
        for (int r = 0; r < 4; ++r)
            dv[r] = (rbase + r < nrows) ? dinv[rbase + r] : 0.f;
        #pragma unroll
        for (int cg = 0; cg < 4; ++cg) {
            int col = wn * 64 + cg * 16 + l15;
            float bv = bias_s[col];
            #pragma unroll
            for (int r = 0; r < 4; ++r) {
                int row = rbase + r;
                if (row < nrows) {
                    outS[(size_t)row * 128 + col] = bf16_rne(accS[mf][cg][r] + bv);
                    outM[(size_t)row * 128 + col] = bf16_rne(accM[mf][cg][r] * dv[r]);
                }
            }
        }
    }
}

// ---------------------------------------------------------------------------
// Aggregation over PRE-SCALED bf16 rows (hw'[j] = dinv_j * hw[j]):
//   r = dinv_i * ( sum_j hw'_j + hw'_i ) + bias
// MODE 0: relu(r)        -> bf16 hi/lo planes   (h1)
// MODE 1: relu(r) + skip -> bf16 hi/lo planes   (h2)
// MODE 2: r              -> fp32 d_out          (F=64 output layer)
// ---------------------------------------------------------------------------
template<int F, int MODE>
__global__ __launch_bounds__(256) void agg_kernel(
    const unsigned short* __restrict__ hws, const int* __restrict__ ell,
    const int* __restrict__ degi, const float* __restrict__ dinv,
    const float* __restrict__ bias, const unsigned short* __restrict__ skip,
    unsigned* __restrict__ outHi, unsigned* __restrict__ outLo,
    float* __restrict__ outF, int n, int dummy)
{
    constexpr int VEC = F / 64;
    constexpr int UNR = 8;
    const int lane = threadIdx.x & 63;
    const int node = blockIdx.x * 4 + (threadIdx.x >> 6);
    if (node >= n) return;

    const int deg  = degi[node];
    const int kmax = deg < ELLW ? deg : ELLW;
    const float di = dinv[node];

    int jpre = dummy;
    if (lane < kmax) jpre = ell[node * ELLW + lane];

    float acc[4][VEC];
    #pragma unroll
    for (int u = 0; u < 4; ++u)
        #pragma unroll
        for (int v = 0; v < VEC; ++v) acc[u][v] = 0.f;

    // self-loop term: hw'_i (already dinv_i-scaled)
    if constexpr (VEC == 2) {
        unsigned p = *(const unsigned*)&hws[(size_t)node * F + lane * 2];
        acc[0][0] = bf16_to_f32((unsigned short)(p & 0xFFFF));
        acc[0][1] = bf16_to_f32((unsigned short)(p >> 16));
    } else {
        acc[0][0] = bf16_to_f32(hws[(size_t)node * F + lane]);
    }

    const int kceil = (kmax + UNR - 1) & ~(UNR - 1);
    for (int k = 0; k < kceil; k += UNR) {
        int jj[UNR];
        #pragma unroll
        for (int u = 0; u < UNR; ++u) jj[u] = __shfl(jpre, k + u);
        if constexpr (VEC == 2) {
            unsigned h[UNR];
            #pragma unroll
            for (int u = 0; u < UNR; ++u)
                h[u] = *(const unsigned*)&hws[(size_t)jj[u] * F + lane * 2];
            #pragma unroll
            for (int u = 0; u < UNR; ++u) {
                acc[u & 3][0] += bf16_to_f32((unsigned short)(h[u] & 0xFFFF));
                acc[u & 3][1] += bf16_to_f32((unsigned short)(h[u] >> 16));
            }
        } else {
            unsigned short h[UNR];
            #pragma unroll
            for (int u = 0; u < UNR; ++u)
                h[u] = hws[(size_t)jj[u] * F + lane];
            #pragma unroll
            for (int u = 0; u < UNR; ++u)
                acc[u & 3][0] += bf16_to_f32(h[u]);
        }
    }

    float r[VEC];
    #pragma unroll
    for (int v = 0; v < VEC; ++v) {
        float s = (acc[0][v] + acc[1][v]) + (acc[2][v] + acc[3][v]);
        r[v] = s * di + bias[lane * VEC + v];
    }

    if constexpr (MODE == 2) {
        outF[(size_t)node * F + lane] = r[0];
    } else {
        #pragma unroll
        for (int v = 0; v < VEC; ++v) {
            r[v] = fmaxf(r[v], 0.f);
            if (MODE == 1) {
                unsigned sp = *(const unsigned*)&skip[(size_t)node * F + lane * 2];
                float sv = (v == 0) ? bf16_to_f32((unsigned short)(sp & 0xFFFF))
                                    : bf16_to_f32((unsigned short)(sp >> 16));
                r[v] += sv;
            }
        }
        unsigned short h0 = bf16_rne(r[0]), h1 = bf16_rne(r[1]);
        unsigned short l0 = bf16_rne(r[0] - bf16_to_f32(h0));
        unsigned short l1 = bf16_rne(r[1] - bf16_to_f32(h1));
        size_t o = (size_t)node * (F / 2) + lane;
        outHi[o] = (unsigned)h0 | ((unsigned)h1 << 16);
        outLo[o] = (unsigned)l0 | ((unsigned)l1 << 16);
    }
}

// ---------------------------------------------------------------------------
extern "C" void kernel_launch(void* const* d_in, const int* in_sizes, int n_in,
                              void* d_out, int out_size, void* d_ws, size_t ws_size,
                              hipStream_t stream)
{
    const float* x  = (const float*)d_in[0];
    const int*   ei = (const int*)  d_in[1];
    const float* W0 = (const float*)d_in[2];
    const float* b0 = (const float*)d_in[3];
    const float* W1 = (const float*)d_in[4];
    const float* b1 = (const float*)d_in[5];
    const float* W2 = (const float*)d_in[6];
    const float* b2 = (const float*)d_in[7];
    const float* Ws = (const float*)d_in[8];
    const float* bs = (const float*)d_in[9];

    const int N = in_sizes[0] / 128;
    const int E = in_sizes[1] / 2;
    const int* src = ei;
    const int* dst = ei + E;

    char* ws = (char*)d_ws;
    auto al = [](size_t v) { return (v + 255) & ~size_t(255); };
    size_t off = 0;
    int*   degi  = (int*)  (ws + off); off = al(off + (size_t)N * 4);
    float* dinv  = (float*)(ws + off); off = al(off + (size_t)N * 4);
    int*   gtail = (int*)  (ws + off); off = al(off + NBUCK * 4);
    int*   ell   = (int*)  (ws + off); off = al(off + (size_t)N * ELLW * 4);
    uint2* part  = (uint2*)(ws + off); off = al(off + (size_t)NBUCK * BCAP * 8);
    unsigned short* pA   = (unsigned short*)(ws + off); off = al(off + ((size_t)N * 128 + 128) * 2);
    unsigned short* pBhi = (unsigned short*)(ws + off); off = al(off + (size_t)N * 128 * 2);
    unsigned short* pBlo = (unsigned short*)(ws + off); off = al(off + (size_t)N * 128 * 2);
    unsigned short* pC   = (unsigned short*)(ws + off); off = al(off + (size_t)N * 128 * 2);
    unsigned short* W0hi = (unsigned short*)(ws + off); off = al(off + 128 * 128 * 2);
    unsigned short* W0lo = (unsigned short*)(ws + off); off = al(off + 128 * 128 * 2);
    unsigned short* W1hi = (unsigned short*)(ws + off); off = al(off + 128 * 128 * 2);
    unsigned short* W1lo = (unsigned short*)(ws + off); off = al(off + 128 * 128 * 2);
    unsigned short* Wshi = (unsigned short*)(ws + off); off = al(off + 128 * 128 * 2);
    unsigned short* Wslo = (unsigned short*)(ws + off); off = al(off + 128 * 128 * 2);
    unsigned short* W2hi = (unsigned short*)(ws + off); off = al(off + 128 * 64 * 2);
    unsigned short* W2lo = (unsigned short*)(ws + off); off = al(off + 128 * 64 * 2);
    (void)ws_size; (void)n_in; (void)out_size;

    hipMemsetAsync(gtail, 0, NBUCK * 4, stream);
    hipMemsetAsync(pA + (size_t)N * 128, 0, 128 * 2, stream);  // zero dummy row
    partition_kernel<<<(E + 2047) / 2048, 256, 0, stream>>>(src, dst, E, part, gtail);
    ell_bucket_kernel<<<(N + BNODES - 1) / BNODES, 512, 0, stream>>>(
        part, gtail, degi, dinv, ell, N);
    split_all_w_kernel<<<224, 256, 0, stream>>>(
        W0, W1, Ws, W2, W0hi, W0lo, W1hi, W1lo, Wshi, Wslo, W2hi, W2lo);

    const int gg  = (N + 127) / 128;
    const int gg2 = (N + 63) / 64;
    const int ga  = (N + 3) / 4;

    // layer 0: hw0' = dinv .* (x@W0);  h1 = relu(di*(sum hw0') + b0)
    mfma_gemm_scaled_kernel<128, true><<<gg, 256, 0, stream>>>(
        x, nullptr, nullptr, W0hi, W0lo, dinv, pA, N);
    agg_kernel<128, 0><<<ga, 256, 0, stream>>>(
        pA, ell, degi, dinv, b0, nullptr, (unsigned*)pBhi, (unsigned*)pBlo, nullptr, N, N);

    // layer 1 (fused): skip = h1@Ws + bs;  hw1' = dinv .* (h1@W1)
    mfma_gemm_dual_kernel<<<gg2, 256, 0, stream>>>(
        pBhi, pBlo, Wshi, Wslo, W1hi, W1lo, bs, dinv, pC, pA, N);
    agg_kernel<128, 1><<<ga, 256, 0, stream>>>(
        pA, ell, degi, dinv, b1, pC, (unsigned*)pBhi, (unsigned*)pBlo, nullptr, N, N);

    // output layer: hw2' = dinv .* (h2@W2);  out = di*(sum hw2') + b2
    mfma_gemm_scaled_kernel<64, false><<<gg, 256, 0, stream>>>(
        nullptr, pBhi, pBlo, W2hi, W2lo, dinv, pA, N);
    agg_kernel<64, 2><<<ga, 256, 0, stream>>>(
        pA, ell, degi, dinv, b2, nullptr, nullptr, nullptr, (float*)d_out, N, 2 * N);
}